// Round 3
// baseline (1328.410 us; speedup 1.0000x reference)
//
#include <hip/hip_runtime.h>
#include <cstdint>
#include <cstddef>
#include <math.h>

#define L_SEQ 4096
#define D_DIM 768
#define B_SZ 8
#define M_ROWS (B_SZ * L_SEQ)   // 32768

typedef __bf16 bf16x8 __attribute__((ext_vector_type(8)));
typedef float floatx4 __attribute__((ext_vector_type(4)));

// ---------------- LayerNorm: one block per row (fp32 in -> bf16 out) ----------------
__global__ __launch_bounds__(256) void ln_kernel(const float* __restrict__ x,
                                                 const float* __restrict__ g,
                                                 const float* __restrict__ b,
                                                 __bf16* __restrict__ xn) {
  __shared__ float red[256];
  const int tid = threadIdx.x;
  const size_t row = blockIdx.x;
  const float* xr = x + row * D_DIM;
  float v0 = xr[tid];
  float v1 = xr[tid + 256];
  float v2 = xr[tid + 512];
  red[tid] = v0 + v1 + v2;
  __syncthreads();
  for (int off = 128; off > 0; off >>= 1) {
    if (tid < off) red[tid] += red[tid + off];
    __syncthreads();
  }
  float mu = red[0] * (1.0f / D_DIM);
  __syncthreads();
  float d0 = v0 - mu, d1 = v1 - mu, d2 = v2 - mu;
  red[tid] = d0 * d0 + d1 * d1 + d2 * d2;
  __syncthreads();
  for (int off = 128; off > 0; off >>= 1) {
    if (tid < off) red[tid] += red[tid + off];
    __syncthreads();
  }
  float rs = rsqrtf(red[0] * (1.0f / D_DIM) + 1e-5f);
  __bf16* xo = xn + row * D_DIM;
  xo[tid]       = (__bf16)(d0 * rs * g[tid]       + b[tid]);
  xo[tid + 256] = (__bf16)(d1 * rs * g[tid + 256] + b[tid + 256]);
  xo[tid + 512] = (__bf16)(d2 * rs * g[tid + 512] + b[tid + 512]);
}

// ---------------- Unified MFMA GEMM ----------------
// MODE 0: GEMM1  — A=xn (M x K=768), Bt=Wi^T (1536 x 768). cols<768 -> xg, cols>=768 -> silu -> zg
// MODE 1: conv fwd — A=xg virtual (M x 2304): A[(b,l)][k*768+i] = xg[b, l+k-1, i] (0-padded)
// MODE 2: conv bwd — A[(b,t)][k*768+i] = xg[b, L-t-k, i] (0-padded)  [flip folded in]
// MODE 3: GEMM2  — A=y (M x 768), Bt=Wo^T, + bias + residual(fp32) -> fp32 out
template<int MODE>
__global__ __launch_bounds__(256) void gemm_kernel(
    const __bf16* __restrict__ A,
    const __bf16* __restrict__ Bt,
    const float* __restrict__ bias,
    const float* __restrict__ resid,
    __bf16* __restrict__ out0,
    __bf16* __restrict__ out1,
    float* __restrict__ outf,
    int K) {
  __shared__ __bf16 As[128 * 40];   // 128 rows x 32 cols, stride 40 (16B aligned rows)
  __shared__ __bf16 Bs[128 * 40];
  const int tid  = threadIdx.x;
  const int tileM = blockIdx.x;
  const int tileN = blockIdx.y;
  const int lane = tid & 63;
  const int wv   = tid >> 6;
  const int wm   = wv >> 1;
  const int wn   = wv & 1;
  const int l15  = lane & 15;
  const int quad = lane >> 4;
  const int sr = tid >> 2;          // staging row 0..63
  const int sc = (tid & 3) * 8;     // staging col offset {0,8,16,24}

  floatx4 acc[4][4];
#pragma unroll
  for (int i = 0; i < 4; ++i)
#pragma unroll
    for (int j = 0; j < 4; ++j)
#pragma unroll
      for (int r = 0; r < 4; ++r) acc[i][j][r] = 0.0f;

  for (int kt = 0; kt < K; kt += 32) {
    __syncthreads();
#pragma unroll
    for (int p = 0; p < 2; ++p) {
      int r = sr + p * 64;
      // ---- A tile ----
      bf16x8 av;
      if (MODE == 1 || MODE == 2) {
        int grow = tileM * 128 + r;
        int bidx = grow >> 12;            // row / 4096
        int l    = grow & (L_SEQ - 1);
        int kblk = kt / D_DIM;            // uniform within tile (768 % 32 == 0)
        int i0   = kt - kblk * D_DIM;
        int lsrc = (MODE == 1) ? (l + kblk - 1) : (L_SEQ - l - kblk);
        if (lsrc >= 0 && lsrc < L_SEQ) {
          av = *(const bf16x8*)(A + ((size_t)(bidx * L_SEQ + lsrc)) * D_DIM + i0 + sc);
        } else {
#pragma unroll
          for (int q = 0; q < 8; ++q) av[q] = (__bf16)0.0f;
        }
      } else {
        size_t grow = (size_t)(tileM * 128 + r);
        av = *(const bf16x8*)(A + grow * (size_t)K + kt + sc);
      }
      *(bf16x8*)(&As[r * 40 + sc]) = av;
      // ---- B tile (Bt is N x K row-major) ----
      size_t gn = (size_t)(tileN * 128 + r);
      bf16x8 bv = *(const bf16x8*)(Bt + gn * (size_t)K + kt + sc);
      *(bf16x8*)(&Bs[r * 40 + sc]) = bv;
    }
    __syncthreads();

    bf16x8 afr[4], bfr[4];
#pragma unroll
    for (int i = 0; i < 4; ++i)
      afr[i] = *(const bf16x8*)(&As[(wm * 64 + i * 16 + l15) * 40 + quad * 8]);
#pragma unroll
    for (int j = 0; j < 4; ++j)
      bfr[j] = *(const bf16x8*)(&Bs[(wn * 64 + j * 16 + l15) * 40 + quad * 8]);
#pragma unroll
    for (int i = 0; i < 4; ++i)
#pragma unroll
      for (int j = 0; j < 4; ++j)
        acc[i][j] = __builtin_amdgcn_mfma_f32_16x16x32_bf16(afr[i], bfr[j], acc[i][j], 0, 0, 0);
  }

  // ---- epilogue: C/D layout col=lane&15, row=quad*4+reg (verified) ----
#pragma unroll
  for (int i = 0; i < 4; ++i) {
#pragma unroll
    for (int j = 0; j < 4; ++j) {
#pragma unroll
      for (int r = 0; r < 4; ++r) {
        int row = tileM * 128 + wm * 64 + i * 16 + quad * 4 + r;
        int col = tileN * 128 + wn * 64 + j * 16 + l15;
        float v = acc[i][j][r] + bias[col];
        if (MODE == 0) {
          if (col < D_DIM) {
            out0[(size_t)row * D_DIM + col] = (__bf16)v;
          } else {
            float s = v / (1.0f + expf(-v));   // silu
            out1[(size_t)row * D_DIM + (col - D_DIM)] = (__bf16)s;
          }
        } else if (MODE == 3) {
          size_t o = (size_t)row * D_DIM + col;
          outf[o] = v + resid[o];              // fp32 output
        } else {
          out0[(size_t)row * D_DIM + col] = (__bf16)v;
        }
      }
    }
  }
}

// ---------------- SSM sequential scan, one thread per (b, d), in-place ----------------
__global__ __launch_bounds__(256) void ssm_kernel(const float* __restrict__ ap,
                                                  const float* __restrict__ bp,
                                                  const float* __restrict__ cp,
                                                  const float* __restrict__ dp,
                                                  __bf16* __restrict__ u) {
  int idx = blockIdx.x * 256 + threadIdx.x;
  if (idx >= B_SZ * D_DIM) return;
  int bidx = idx / D_DIM;
  int d = idx - bidx * D_DIM;
  float a  = 1.0f / (1.0f + expf(-ap[d]));
  float bb = bp[d];
  float cc = cp[d];
  float dd = dp[d];
  __bf16* ub = u + (size_t)bidx * L_SEQ * D_DIM + d;
  float h = 0.0f;
  for (int l = 0; l < L_SEQ; ++l) {
    float uv = (float)ub[(size_t)l * D_DIM];
    h = a * h + bb * uv;
    ub[(size_t)l * D_DIM] = (__bf16)(cc * h + dd * uv);
  }
}

// ---------------- gating: y = (f + flip_L(bb)) * zg ----------------
__global__ __launch_bounds__(256) void gate_kernel(const __bf16* __restrict__ f,
                                                   const __bf16* __restrict__ bbuf,
                                                   const __bf16* __restrict__ zg,
                                                   __bf16* __restrict__ y) {
  size_t idx = (size_t)blockIdx.x * 256 + threadIdx.x;
  int d = (int)(idx % D_DIM);
  size_t rl = idx / D_DIM;
  int l = (int)(rl & (L_SEQ - 1));
  size_t b = rl >> 12;
  size_t src = ((b << 12) + (size_t)(L_SEQ - 1 - l)) * D_DIM + d;
  float v = ((float)f[idx] + (float)bbuf[src]) * (float)zg[idx];
  y[idx] = (__bf16)v;
}

// ---------------- weight transposes (fp32 in -> bf16 out) ----------------
// out[n][k] = in[k][n]; in is Kdim x Ndim row-major
__global__ __launch_bounds__(256) void tr_kernel(const float* __restrict__ in,
                                                 __bf16* __restrict__ out,
                                                 int Kdim, int Ndim) {
  int idx = blockIdx.x * 256 + threadIdx.x;
  if (idx >= Kdim * Ndim) return;
  int n = idx / Kdim;
  int k = idx - n * Kdim;
  out[idx] = (__bf16)in[(size_t)k * Ndim + n];
}

// conv weight (O=768, I=768, W=3) -> out[o][k*768 + i] = in[o*2304 + i*3 + k]
__global__ __launch_bounds__(256) void trconv_kernel(const float* __restrict__ in,
                                                     __bf16* __restrict__ out) {
  int idx = blockIdx.x * 256 + threadIdx.x;
  if (idx >= D_DIM * 2304) return;
  int o = idx / 2304;
  int rem = idx - o * 2304;
  int k = rem / D_DIM;
  int i = rem - k * D_DIM;
  out[idx] = (__bf16)in[(size_t)o * 2304 + i * 3 + k];
}

extern "C" void kernel_launch(void* const* d_in, const int* in_sizes, int n_in,
                              void* d_out, int out_size, void* d_ws, size_t ws_size,
                              hipStream_t stream) {
  const float* x    = (const float*)d_in[0];
  const float* ln_g = (const float*)d_in[1];
  const float* ln_b = (const float*)d_in[2];
  const float* Wi   = (const float*)d_in[3];
  const float* bi   = (const float*)d_in[4];
  const float* Wf   = (const float*)d_in[5];
  const float* bfc  = (const float*)d_in[6];
  const float* af   = (const float*)d_in[7];
  const float* bfp  = (const float*)d_in[8];
  const float* cfp  = (const float*)d_in[9];
  const float* dfp  = (const float*)d_in[10];
  const float* Wb   = (const float*)d_in[11];
  const float* bbc  = (const float*)d_in[12];
  const float* ab   = (const float*)d_in[13];
  const float* bbp  = (const float*)d_in[14];
  const float* cbp  = (const float*)d_in[15];
  const float* dbp  = (const float*)d_in[16];
  const float* Wo   = (const float*)d_in[17];
  const float* bo   = (const float*)d_in[18];
  float* out = (float*)d_out;   // reference output dtype is float32

  char* ws = (char*)d_ws;
  const size_t BLD = (size_t)B_SZ * L_SEQ * D_DIM;   // 25165824
  __bf16* ws0 = (__bf16*)(ws);                       // xn, then f
  __bf16* ws1 = (__bf16*)(ws + BLD * 2);             // xg, then y
  __bf16* ws2 = (__bf16*)(ws + BLD * 4);             // zg (silu applied)
  __bf16* ws3 = (__bf16*)(ws + BLD * 6);             // bbuf (flipped-time order)
  __bf16* wit = (__bf16*)(ws + BLD * 8);             // Wi^T  (1536 x 768)
  __bf16* wft = wit + (size_t)1536 * 768;            // Wf reshaped (768 x 2304)
  __bf16* wbt = wft + (size_t)768 * 2304;            // Wb reshaped
  __bf16* wot = wbt + (size_t)768 * 2304;            // Wo^T (768 x 768)
  const size_t needed = BLD * 8 +
      ((size_t)1536 * 768 + 2 * (size_t)768 * 2304 + (size_t)768 * 768) * 2;
  if (ws_size < needed) return;  // fail loudly (output stays zero)

  // weight reshapes (fp32 -> bf16, rerun every launch)
  tr_kernel<<<(768 * 1536 + 255) / 256, 256, 0, stream>>>(Wi, wit, 768, 1536);
  trconv_kernel<<<(768 * 2304 + 255) / 256, 256, 0, stream>>>(Wf, wft);
  trconv_kernel<<<(768 * 2304 + 255) / 256, 256, 0, stream>>>(Wb, wbt);
  tr_kernel<<<(768 * 768 + 255) / 256, 256, 0, stream>>>(Wo, wot, 768, 768);

  // LayerNorm
  ln_kernel<<<M_ROWS, 256, 0, stream>>>(x, ln_g, ln_b, ws0);

  // proj = xn@Wi + bi -> xg (ws1), zg = silu(z) (ws2)
  gemm_kernel<0><<<dim3(M_ROWS / 128, 1536 / 128), 256, 0, stream>>>(
      ws0, wit, bi, nullptr, ws1, ws2, nullptr, 768);

  // forward conv -> f (ws0); backward conv (flip folded into indexing) -> bbuf (ws3)
  gemm_kernel<1><<<dim3(M_ROWS / 128, 768 / 128), 256, 0, stream>>>(
      ws1, wft, bfc, nullptr, ws0, nullptr, nullptr, 2304);
  gemm_kernel<2><<<dim3(M_ROWS / 128, 768 / 128), 256, 0, stream>>>(
      ws1, wbt, bbc, nullptr, ws3, nullptr, nullptr, 2304);

  // SSM scans in-place
  ssm_kernel<<<(B_SZ * D_DIM + 255) / 256, 256, 0, stream>>>(af, bfp, cfp, dfp, ws0);
  ssm_kernel<<<(B_SZ * D_DIM + 255) / 256, 256, 0, stream>>>(ab, bbp, cbp, dbp, ws3);

  // y = (f + flip(bb)) * zg -> ws1
  gate_kernel<<<(unsigned)(BLD / 256), 256, 0, stream>>>(ws0, ws3, ws2, ws1);

  // out = y@Wo + bo + x  (fp32 output)
  gemm_kernel<3><<<dim3(M_ROWS / 128, 768 / 128), 256, 0, stream>>>(
      ws1, wot, bo, x, nullptr, nullptr, out, 768);
}

// Round 4
// 901.668 us; speedup vs baseline: 1.4733x; 1.4733x over previous
//
#include <hip/hip_runtime.h>
#include <cstdint>
#include <cstddef>
#include <math.h>

#define L_SEQ 4096
#define D_DIM 768
#define B_SZ 8
#define M_ROWS (B_SZ * L_SEQ)   // 32768
#define CHUNK 64                 // scan chunk length; 64 chunks of 64 over L=4096

typedef __bf16 bf16x8 __attribute__((ext_vector_type(8)));
typedef float floatx4 __attribute__((ext_vector_type(4)));

// ---------------- LayerNorm: one block per row (fp32 in -> bf16 out) ----------------
__global__ __launch_bounds__(256) void ln_kernel(const float* __restrict__ x,
                                                 const float* __restrict__ g,
                                                 const float* __restrict__ b,
                                                 __bf16* __restrict__ xn) {
  __shared__ float red[256];
  const int tid = threadIdx.x;
  const size_t row = blockIdx.x;
  const float* xr = x + row * D_DIM;
  float v0 = xr[tid];
  float v1 = xr[tid + 256];
  float v2 = xr[tid + 512];
  red[tid] = v0 + v1 + v2;
  __syncthreads();
  for (int off = 128; off > 0; off >>= 1) {
    if (tid < off) red[tid] += red[tid + off];
    __syncthreads();
  }
  float mu = red[0] * (1.0f / D_DIM);
  __syncthreads();
  float d0 = v0 - mu, d1 = v1 - mu, d2 = v2 - mu;
  red[tid] = d0 * d0 + d1 * d1 + d2 * d2;
  __syncthreads();
  for (int off = 128; off > 0; off >>= 1) {
    if (tid < off) red[tid] += red[tid + off];
    __syncthreads();
  }
  float rs = rsqrtf(red[0] * (1.0f / D_DIM) + 1e-5f);
  __bf16* xo = xn + row * D_DIM;
  xo[tid]       = (__bf16)(d0 * rs * g[tid]       + b[tid]);
  xo[tid + 256] = (__bf16)(d1 * rs * g[tid + 256] + b[tid + 256]);
  xo[tid + 512] = (__bf16)(d2 * rs * g[tid + 512] + b[tid + 512]);
}

// ---------------- Unified MFMA GEMM ----------------
// MODE 0: GEMM1  — A=xn (M x K=768), Bt=Wi^T (1536 x 768). cols<768 -> xg, cols>=768 -> silu -> zg
// MODE 1: conv fwd — A=xg virtual (M x 2304): A[(b,l)][k*768+i] = xg[b, l+k-1, i] (0-padded)
// MODE 2: conv bwd — A[(b,t)][k*768+i] = xg[b, L-t-k, i] (0-padded)  [flip folded in]
// MODE 3: GEMM2  — A=y (M x 768), Bt=Wo^T, + bias + residual(fp32) -> fp32 out
template<int MODE>
__global__ __launch_bounds__(256) void gemm_kernel(
    const __bf16* __restrict__ A,
    const __bf16* __restrict__ Bt,
    const float* __restrict__ bias,
    const float* __restrict__ resid,
    __bf16* __restrict__ out0,
    __bf16* __restrict__ out1,
    float* __restrict__ outf,
    int K) {
  __shared__ __bf16 As[128 * 40];   // 128 rows x 32 cols, stride 40 (16B aligned rows)
  __shared__ __bf16 Bs[128 * 40];
  const int tid  = threadIdx.x;
  const int tileM = blockIdx.x;
  const int tileN = blockIdx.y;
  const int lane = tid & 63;
  const int wv   = tid >> 6;
  const int wm   = wv >> 1;
  const int wn   = wv & 1;
  const int l15  = lane & 15;
  const int quad = lane >> 4;
  const int sr = tid >> 2;          // staging row 0..63
  const int sc = (tid & 3) * 8;     // staging col offset {0,8,16,24}

  floatx4 acc[4][4];
#pragma unroll
  for (int i = 0; i < 4; ++i)
#pragma unroll
    for (int j = 0; j < 4; ++j)
#pragma unroll
      for (int r = 0; r < 4; ++r) acc[i][j][r] = 0.0f;

  for (int kt = 0; kt < K; kt += 32) {
    __syncthreads();
#pragma unroll
    for (int p = 0; p < 2; ++p) {
      int r = sr + p * 64;
      // ---- A tile ----
      bf16x8 av;
      if (MODE == 1 || MODE == 2) {
        int grow = tileM * 128 + r;
        int bidx = grow >> 12;            // row / 4096
        int l    = grow & (L_SEQ - 1);
        int kblk = kt / D_DIM;            // uniform within tile (768 % 32 == 0)
        int i0   = kt - kblk * D_DIM;
        int lsrc = (MODE == 1) ? (l + kblk - 1) : (L_SEQ - l - kblk);
        if (lsrc >= 0 && lsrc < L_SEQ) {
          av = *(const bf16x8*)(A + ((size_t)(bidx * L_SEQ + lsrc)) * D_DIM + i0 + sc);
        } else {
#pragma unroll
          for (int q = 0; q < 8; ++q) av[q] = (__bf16)0.0f;
        }
      } else {
        size_t grow = (size_t)(tileM * 128 + r);
        av = *(const bf16x8*)(A + grow * (size_t)K + kt + sc);
      }
      *(bf16x8*)(&As[r * 40 + sc]) = av;
      // ---- B tile (Bt is N x K row-major) ----
      size_t gn = (size_t)(tileN * 128 + r);
      bf16x8 bv = *(const bf16x8*)(Bt + gn * (size_t)K + kt + sc);
      *(bf16x8*)(&Bs[r * 40 + sc]) = bv;
    }
    __syncthreads();

    bf16x8 afr[4], bfr[4];
#pragma unroll
    for (int i = 0; i < 4; ++i)
      afr[i] = *(const bf16x8*)(&As[(wm * 64 + i * 16 + l15) * 40 + quad * 8]);
#pragma unroll
    for (int j = 0; j < 4; ++j)
      bfr[j] = *(const bf16x8*)(&Bs[(wn * 64 + j * 16 + l15) * 40 + quad * 8]);
#pragma unroll
    for (int i = 0; i < 4; ++i)
#pragma unroll
      for (int j = 0; j < 4; ++j)
        acc[i][j] = __builtin_amdgcn_mfma_f32_16x16x32_bf16(afr[i], bfr[j], acc[i][j], 0, 0, 0);
  }

  // ---- epilogue: C/D layout col=lane&15, row=quad*4+reg (verified) ----
#pragma unroll
  for (int i = 0; i < 4; ++i) {
#pragma unroll
    for (int j = 0; j < 4; ++j) {
#pragma unroll
      for (int r = 0; r < 4; ++r) {
        int row = tileM * 128 + wm * 64 + i * 16 + quad * 4 + r;
        int col = tileN * 128 + wn * 64 + j * 16 + l15;
        float v = acc[i][j][r] + bias[col];
        if (MODE == 0) {
          if (col < D_DIM) {
            out0[(size_t)row * D_DIM + col] = (__bf16)v;
          } else {
            float s = v / (1.0f + expf(-v));   // silu
            out1[(size_t)row * D_DIM + (col - D_DIM)] = (__bf16)s;
          }
        } else if (MODE == 3) {
          size_t o = (size_t)row * D_DIM + col;
          outf[o] = v + resid[o];              // fp32 output
        } else {
          out0[(size_t)row * D_DIM + col] = (__bf16)v;
        }
      }
    }
  }
}

// ---------------- Chunked parallel SSM scan ----------------
// Linear recurrence h_t = a h_{t-1} + b u_t decomposes over chunks of T=64:
// h_out = a^T h_in + h_local. Both directions (f in u0, bbuf in u1) fused per launch.
// Thread mapping (all passes): idx = ((tensor*8 + b)*64 + chunk)*768 + d
// hl scratch layout == flat idx (fp32, 3.1 MB), lives in dead ws1 region.

__global__ __launch_bounds__(256) void scan1_kernel(
    const float* __restrict__ ap0, const float* __restrict__ bp0,
    const float* __restrict__ ap1, const float* __restrict__ bp1,
    const __bf16* __restrict__ u0, const __bf16* __restrict__ u1,
    float* __restrict__ hl) {
  int idx = blockIdx.x * 256 + threadIdx.x;
  int d = idx % D_DIM;
  int rest = idx / D_DIM;        // (tensor*8 + b)*64 + chunk, 0..1023
  int chunk = rest & 63;
  int tb = rest >> 6;            // tensor*8 + b
  int b = tb & 7;
  int tensor = tb >> 3;
  const float* ap = tensor ? ap1 : ap0;
  const float* bp = tensor ? bp1 : bp0;
  const __bf16* u = (tensor ? u1 : u0) +
      ((size_t)(b * L_SEQ + chunk * CHUNK)) * D_DIM + d;
  float a  = 1.0f / (1.0f + expf(-ap[d]));
  float bb = bp[d];
  float h = 0.0f;
  for (int t = 0; t < CHUNK; ++t) {
    h = a * h + bb * (float)u[(size_t)t * D_DIM];
  }
  hl[(size_t)idx] = h;
}

__global__ __launch_bounds__(256) void scan2_kernel(
    const float* __restrict__ ap0, const float* __restrict__ ap1,
    float* __restrict__ hl) {
  int idx = blockIdx.x * 256 + threadIdx.x;   // 2*8*768 = 12288 threads
  int d = idx % D_DIM;
  int tb = idx / D_DIM;          // tensor*8 + b
  int tensor = tb >> 3;
  const float* ap = tensor ? ap1 : ap0;
  float a = 1.0f / (1.0f + expf(-ap[d]));
  // a^64 by repeated squaring
  float aT = a * a;              // a^2
  aT = aT * aT;                  // a^4
  aT = aT * aT;                  // a^8
  aT = aT * aT;                  // a^16
  aT = aT * aT;                  // a^32
  aT = aT * aT;                  // a^64
  float* base = hl + (size_t)tb * 64 * D_DIM + d;
  float carry = 0.0f;            // state entering chunk 0
  for (int c = 0; c < 64; ++c) {
    float* p = base + (size_t)c * D_DIM;
    float tmp = *p;              // local final of chunk c
    *p = carry;                  // state entering chunk c
    carry = aT * carry + tmp;    // state entering chunk c+1
  }
}

__global__ __launch_bounds__(256) void scan3_kernel(
    const float* __restrict__ ap0, const float* __restrict__ bp0,
    const float* __restrict__ cp0, const float* __restrict__ dp0,
    const float* __restrict__ ap1, const float* __restrict__ bp1,
    const float* __restrict__ cp1, const float* __restrict__ dp1,
    __bf16* __restrict__ u0, __bf16* __restrict__ u1,
    const float* __restrict__ hl) {
  int idx = blockIdx.x * 256 + threadIdx.x;
  int d = idx % D_DIM;
  int rest = idx / D_DIM;
  int chunk = rest & 63;
  int tb = rest >> 6;
  int b = tb & 7;
  int tensor = tb >> 3;
  const float* ap = tensor ? ap1 : ap0;
  const float* bp = tensor ? bp1 : bp0;
  const float* cp = tensor ? cp1 : cp0;
  const float* dp = tensor ? dp1 : dp0;
  __bf16* u = (tensor ? u1 : u0) +
      ((size_t)(b * L_SEQ + chunk * CHUNK)) * D_DIM + d;
  float a  = 1.0f / (1.0f + expf(-ap[d]));
  float bb = bp[d];
  float cc = cp[d];
  float dd = dp[d];
  float h = hl[(size_t)idx];
  for (int t = 0; t < CHUNK; ++t) {
    float uv = (float)u[(size_t)t * D_DIM];
    h = a * h + bb * uv;
    u[(size_t)t * D_DIM] = (__bf16)(cc * h + dd * uv);
  }
}

// ---------------- gating: y = (f + flip_L(bb)) * zg ----------------
__global__ __launch_bounds__(256) void gate_kernel(const __bf16* __restrict__ f,
                                                   const __bf16* __restrict__ bbuf,
                                                   const __bf16* __restrict__ zg,
                                                   __bf16* __restrict__ y) {
  size_t idx = (size_t)blockIdx.x * 256 + threadIdx.x;
  int d = (int)(idx % D_DIM);
  size_t rl = idx / D_DIM;
  int l = (int)(rl & (L_SEQ - 1));
  size_t b = rl >> 12;
  size_t src = ((b << 12) + (size_t)(L_SEQ - 1 - l)) * D_DIM + d;
  float v = ((float)f[idx] + (float)bbuf[src]) * (float)zg[idx];
  y[idx] = (__bf16)v;
}

// ---------------- weight transposes (fp32 in -> bf16 out) ----------------
// out[n][k] = in[k][n]; in is Kdim x Ndim row-major
__global__ __launch_bounds__(256) void tr_kernel(const float* __restrict__ in,
                                                 __bf16* __restrict__ out,
                                                 int Kdim, int Ndim) {
  int idx = blockIdx.x * 256 + threadIdx.x;
  if (idx >= Kdim * Ndim) return;
  int n = idx / Kdim;
  int k = idx - n * Kdim;
  out[idx] = (__bf16)in[(size_t)k * Ndim + n];
}

// conv weight (O=768, I=768, W=3) -> out[o][k*768 + i] = in[o*2304 + i*3 + k]
__global__ __launch_bounds__(256) void trconv_kernel(const float* __restrict__ in,
                                                     __bf16* __restrict__ out) {
  int idx = blockIdx.x * 256 + threadIdx.x;
  if (idx >= D_DIM * 2304) return;
  int o = idx / 2304;
  int rem = idx - o * 2304;
  int k = rem / D_DIM;
  int i = rem - k * D_DIM;
  out[idx] = (__bf16)in[(size_t)o * 2304 + i * 3 + k];
}

extern "C" void kernel_launch(void* const* d_in, const int* in_sizes, int n_in,
                              void* d_out, int out_size, void* d_ws, size_t ws_size,
                              hipStream_t stream) {
  const float* x    = (const float*)d_in[0];
  const float* ln_g = (const float*)d_in[1];
  const float* ln_b = (const float*)d_in[2];
  const float* Wi   = (const float*)d_in[3];
  const float* bi   = (const float*)d_in[4];
  const float* Wf   = (const float*)d_in[5];
  const float* bfc  = (const float*)d_in[6];
  const float* af   = (const float*)d_in[7];
  const float* bfp  = (const float*)d_in[8];
  const float* cfp  = (const float*)d_in[9];
  const float* dfp  = (const float*)d_in[10];
  const float* Wb   = (const float*)d_in[11];
  const float* bbc  = (const float*)d_in[12];
  const float* ab   = (const float*)d_in[13];
  const float* bbp  = (const float*)d_in[14];
  const float* cbp  = (const float*)d_in[15];
  const float* dbp  = (const float*)d_in[16];
  const float* Wo   = (const float*)d_in[17];
  const float* bo   = (const float*)d_in[18];
  float* out = (float*)d_out;   // reference output dtype is float32

  char* ws = (char*)d_ws;
  const size_t BLD = (size_t)B_SZ * L_SEQ * D_DIM;   // 25165824
  __bf16* ws0 = (__bf16*)(ws);                       // xn, then f
  __bf16* ws1 = (__bf16*)(ws + BLD * 2);             // xg, then y
  __bf16* ws2 = (__bf16*)(ws + BLD * 4);             // zg (silu applied)
  __bf16* ws3 = (__bf16*)(ws + BLD * 6);             // bbuf (flipped-time order)
  __bf16* wit = (__bf16*)(ws + BLD * 8);             // Wi^T  (1536 x 768)
  __bf16* wft = wit + (size_t)1536 * 768;            // Wf reshaped (768 x 2304)
  __bf16* wbt = wft + (size_t)768 * 2304;            // Wb reshaped
  __bf16* wot = wbt + (size_t)768 * 2304;            // Wo^T (768 x 768)
  // scan scratch: 2*8*64*768 fp32 = 3.1 MB, aliases ws1 (xg is dead by scan time)
  float* hl = (float*)(ws + BLD * 2);
  const size_t needed = BLD * 8 +
      ((size_t)1536 * 768 + 2 * (size_t)768 * 2304 + (size_t)768 * 768) * 2;
  if (ws_size < needed) return;  // fail loudly (output stays zero)

  // weight reshapes (fp32 -> bf16, rerun every launch)
  tr_kernel<<<(768 * 1536 + 255) / 256, 256, 0, stream>>>(Wi, wit, 768, 1536);
  trconv_kernel<<<(768 * 2304 + 255) / 256, 256, 0, stream>>>(Wf, wft);
  trconv_kernel<<<(768 * 2304 + 255) / 256, 256, 0, stream>>>(Wb, wbt);
  tr_kernel<<<(768 * 768 + 255) / 256, 256, 0, stream>>>(Wo, wot, 768, 768);

  // LayerNorm
  ln_kernel<<<M_ROWS, 256, 0, stream>>>(x, ln_g, ln_b, ws0);

  // proj = xn@Wi + bi -> xg (ws1), zg = silu(z) (ws2)
  gemm_kernel<0><<<dim3(M_ROWS / 128, 1536 / 128), 256, 0, stream>>>(
      ws0, wit, bi, nullptr, ws1, ws2, nullptr, 768);

  // forward conv -> f (ws0); backward conv (flip folded into indexing) -> bbuf (ws3)
  gemm_kernel<1><<<dim3(M_ROWS / 128, 768 / 128), 256, 0, stream>>>(
      ws1, wft, bfc, nullptr, ws0, nullptr, nullptr, 2304);
  gemm_kernel<2><<<dim3(M_ROWS / 128, 768 / 128), 256, 0, stream>>>(
      ws1, wbt, bbc, nullptr, ws3, nullptr, nullptr, 2304);

  // Chunked parallel SSM scans (both directions per launch), in-place on ws0/ws3
  {
    const int n1 = 2 * B_SZ * 64 * D_DIM;       // 786432
    scan1_kernel<<<n1 / 256, 256, 0, stream>>>(af, bfp, ab, bbp, ws0, ws3, hl);
    const int n2 = 2 * B_SZ * D_DIM;            // 12288
    scan2_kernel<<<n2 / 256, 256, 0, stream>>>(af, ab, hl);
    scan3_kernel<<<n1 / 256, 256, 0, stream>>>(af, bfp, cfp, dfp,
                                               ab, bbp, cbp, dbp,
                                               ws0, ws3, hl);
  }

  // y = (f + flip(bb)) * zg -> ws1
  gate_kernel<<<(unsigned)(BLD / 256), 256, 0, stream>>>(ws0, ws3, ws2, ws1);

  // out = y@Wo + bo + x  (fp32 output)
  gemm_kernel<3><<<dim3(M_ROWS / 128, 768 / 128), 256, 0, stream>>>(
      ws1, wot, bo, x, nullptr, nullptr, out, 768);
}

// Round 5
// 880.500 us; speedup vs baseline: 1.5087x; 1.0240x over previous
//
#include <hip/hip_runtime.h>
#include <cstdint>
#include <cstddef>
#include <math.h>

#define L_SEQ 4096
#define D_DIM 768
#define B_SZ 8
#define M_ROWS (B_SZ * L_SEQ)   // 32768
#define CHUNK 64                 // scan chunk length; 64 chunks of 64 over L=4096

typedef __bf16 bf16x8 __attribute__((ext_vector_type(8)));
typedef float floatx4 __attribute__((ext_vector_type(4)));

#define GLP(p)  ((__attribute__((address_space(1))) const void*)(const void*)(p))
#define LDSP(p) ((__attribute__((address_space(3))) void*)(void*)(p))

// ---------------- LayerNorm: one block per row (fp32 in -> bf16 out) ----------------
__global__ __launch_bounds__(256) void ln_kernel(const float* __restrict__ x,
                                                 const float* __restrict__ g,
                                                 const float* __restrict__ b,
                                                 __bf16* __restrict__ xn) {
  __shared__ float red[256];
  const int tid = threadIdx.x;
  const size_t row = blockIdx.x;
  const float* xr = x + row * D_DIM;
  float v0 = xr[tid];
  float v1 = xr[tid + 256];
  float v2 = xr[tid + 512];
  red[tid] = v0 + v1 + v2;
  __syncthreads();
  for (int off = 128; off > 0; off >>= 1) {
    if (tid < off) red[tid] += red[tid + off];
    __syncthreads();
  }
  float mu = red[0] * (1.0f / D_DIM);
  __syncthreads();
  float d0 = v0 - mu, d1 = v1 - mu, d2 = v2 - mu;
  red[tid] = d0 * d0 + d1 * d1 + d2 * d2;
  __syncthreads();
  for (int off = 128; off > 0; off >>= 1) {
    if (tid < off) red[tid] += red[tid + off];
    __syncthreads();
  }
  float rs = rsqrtf(red[0] * (1.0f / D_DIM) + 1e-5f);
  __bf16* xo = xn + row * D_DIM;
  xo[tid]       = (__bf16)(d0 * rs * g[tid]       + b[tid]);
  xo[tid + 256] = (__bf16)(d1 * rs * g[tid + 256] + b[tid + 256]);
  xo[tid + 512] = (__bf16)(d2 * rs * g[tid + 512] + b[tid + 512]);
}

// ---------------- Unified MFMA GEMM (global_load_lds staging) ----------------
// MODE 0: GEMM1  — A=xn (M x 768), Bt=Wi^T (1536 x 768). col<768 -> xg, col>=768 -> silu -> zg
// MODE 1: conv fwd — A[(b,l)][k*768+i] = xg[b, l+k-1, i] (0-padded)
// MODE 2: conv bwd — A[(b,t)][k*768+i] = xg[b, L-t-k, i] (0-padded) [flip folded in]
// MODE 3: GEMM2  — A=y (M x 768), Bt=Wo^T, + bias + residual(fp32) -> fp32 out
// Grid: (Ntiles, Mtiles) — tileN on fast axis so blocks sharing an A-tile dispatch together.
template<int MODE>
__global__ __launch_bounds__(256) void gemm_kernel(
    const __bf16* __restrict__ A,
    const __bf16* __restrict__ Bt,
    const float* __restrict__ bias,
    const float* __restrict__ resid,
    __bf16* __restrict__ out0,
    __bf16* __restrict__ out1,
    float* __restrict__ outf,
    const __bf16* __restrict__ zbuf,
    int K) {
  __shared__ __bf16 As[128 * 32];   // unpadded: required by global_load_lds lane mapping
  __shared__ __bf16 Bs[128 * 32];
  const int tid   = threadIdx.x;
  const int tileN = blockIdx.x;
  const int tileM = blockIdx.y;
  const int lane = tid & 63;
  const int w    = tid >> 6;
  const int wm   = w >> 1;
  const int wn   = w & 1;
  const int l15  = lane & 15;
  const int quad = lane >> 4;
  const int colg = (lane & 3) * 8;   // element col offset {0,8,16,24}
  const int rsub = lane >> 2;        // 0..15 row within 16-row slab

  // staging rows: wave w, instr p cover LDS rows [w*32+p*16, +16)
  const int rowA0 = w * 32 + rsub;
  const int rowA1 = rowA0 + 16;

  const __bf16* gB0 = Bt + (size_t)(tileN * 128 + rowA0) * K + colg;
  const __bf16* gB1 = Bt + (size_t)(tileN * 128 + rowA1) * K + colg;

  const __bf16* gA0 = nullptr;
  const __bf16* gA1 = nullptr;
  int bl0 = 0, bl1 = 0, l0 = 0, l1 = 0;
  if (MODE == 1 || MODE == 2) {
    int gr0 = tileM * 128 + rowA0;
    int gr1 = tileM * 128 + rowA1;
    bl0 = gr0 >> 12; l0 = gr0 & (L_SEQ - 1);
    bl1 = gr1 >> 12; l1 = gr1 & (L_SEQ - 1);
  } else {
    gA0 = A + (size_t)(tileM * 128 + rowA0) * K + colg;
    gA1 = A + (size_t)(tileM * 128 + rowA1) * K + colg;
  }

  __bf16* ldsA0 = &As[(w * 32) * 32];
  __bf16* ldsA1 = &As[(w * 32 + 16) * 32];
  __bf16* ldsB0 = &Bs[(w * 32) * 32];
  __bf16* ldsB1 = &Bs[(w * 32 + 16) * 32];

  floatx4 acc[4][4];
#pragma unroll
  for (int i = 0; i < 4; ++i)
#pragma unroll
    for (int j = 0; j < 4; ++j)
#pragma unroll
      for (int r = 0; r < 4; ++r) acc[i][j][r] = 0.0f;

  int kblk = 0, i0 = 0;
  for (int kt = 0; kt < K; kt += 32) {
    __syncthreads();   // previous iter's ds_reads done before overwrite
    const __bf16* pa0;
    const __bf16* pa1;
    if (MODE == 1 || MODE == 2) {
      int ls0 = (MODE == 1) ? (l0 + kblk - 1) : (L_SEQ - l0 - kblk);
      int ls1 = (MODE == 1) ? (l1 + kblk - 1) : (L_SEQ - l1 - kblk);
      pa0 = (ls0 >= 0 && ls0 < L_SEQ)
          ? A + ((size_t)(bl0 << 12) + (size_t)ls0) * D_DIM + i0 + colg : zbuf;
      pa1 = (ls1 >= 0 && ls1 < L_SEQ)
          ? A + ((size_t)(bl1 << 12) + (size_t)ls1) * D_DIM + i0 + colg : zbuf;
    } else {
      pa0 = gA0 + kt;
      pa1 = gA1 + kt;
    }
    __builtin_amdgcn_global_load_lds(GLP(pa0), LDSP(ldsA0), 16, 0, 0);
    __builtin_amdgcn_global_load_lds(GLP(pa1), LDSP(ldsA1), 16, 0, 0);
    __builtin_amdgcn_global_load_lds(GLP(gB0 + kt), LDSP(ldsB0), 16, 0, 0);
    __builtin_amdgcn_global_load_lds(GLP(gB1 + kt), LDSP(ldsB1), 16, 0, 0);
    __syncthreads();   // implicit vmcnt(0) drain completes the DMA

    bf16x8 afr[4], bfr[4];
#pragma unroll
    for (int i = 0; i < 4; ++i)
      afr[i] = *(const bf16x8*)(&As[(wm * 64 + i * 16 + l15) * 32 + quad * 8]);
#pragma unroll
    for (int j = 0; j < 4; ++j)
      bfr[j] = *(const bf16x8*)(&Bs[(wn * 64 + j * 16 + l15) * 32 + quad * 8]);
#pragma unroll
    for (int i = 0; i < 4; ++i)
#pragma unroll
      for (int j = 0; j < 4; ++j)
        acc[i][j] = __builtin_amdgcn_mfma_f32_16x16x32_bf16(afr[i], bfr[j], acc[i][j], 0, 0, 0);

    i0 += 32;
    if (i0 == D_DIM) { i0 = 0; ++kblk; }
  }

  // ---- epilogue: C/D layout col=lane&15, row=quad*4+reg (verified) ----
#pragma unroll
  for (int i = 0; i < 4; ++i) {
#pragma unroll
    for (int j = 0; j < 4; ++j) {
#pragma unroll
      for (int r = 0; r < 4; ++r) {
        int row = tileM * 128 + wm * 64 + i * 16 + quad * 4 + r;
        int col = tileN * 128 + wn * 64 + j * 16 + l15;
        float v = acc[i][j][r] + bias[col];
        if (MODE == 0) {
          if (col < D_DIM) {
            out0[(size_t)row * D_DIM + col] = (__bf16)v;
          } else {
            float s = v / (1.0f + expf(-v));   // silu
            out1[(size_t)row * D_DIM + (col - D_DIM)] = (__bf16)s;
          }
        } else if (MODE == 3) {
          size_t o = (size_t)row * D_DIM + col;
          outf[o] = v + resid[o];              // fp32 output
        } else {
          out0[(size_t)row * D_DIM + col] = (__bf16)v;
        }
      }
    }
  }
}

// ---------------- Chunked parallel SSM scan ----------------
__global__ __launch_bounds__(256) void scan1_kernel(
    const float* __restrict__ ap0, const float* __restrict__ bp0,
    const float* __restrict__ ap1, const float* __restrict__ bp1,
    const __bf16* __restrict__ u0, const __bf16* __restrict__ u1,
    float* __restrict__ hl) {
  int idx = blockIdx.x * 256 + threadIdx.x;
  int d = idx % D_DIM;
  int rest = idx / D_DIM;
  int chunk = rest & 63;
  int tb = rest >> 6;
  int b = tb & 7;
  int tensor = tb >> 3;
  const float* ap = tensor ? ap1 : ap0;
  const float* bp = tensor ? bp1 : bp0;
  const __bf16* u = (tensor ? u1 : u0) +
      ((size_t)(b * L_SEQ + chunk * CHUNK)) * D_DIM + d;
  float a  = 1.0f / (1.0f + expf(-ap[d]));
  float bb = bp[d];
  float h = 0.0f;
  for (int t = 0; t < CHUNK; ++t) {
    h = a * h + bb * (float)u[(size_t)t * D_DIM];
  }
  hl[(size_t)idx] = h;
}

__global__ __launch_bounds__(256) void scan2_kernel(
    const float* __restrict__ ap0, const float* __restrict__ ap1,
    float* __restrict__ hl) {
  int idx = blockIdx.x * 256 + threadIdx.x;
  int d = idx % D_DIM;
  int tb = idx / D_DIM;
  int tensor = tb >> 3;
  const float* ap = tensor ? ap1 : ap0;
  float a = 1.0f / (1.0f + expf(-ap[d]));
  float aT = a * a;  aT = aT * aT;  aT = aT * aT;
  aT = aT * aT;      aT = aT * aT;  aT = aT * aT;   // a^64
  float* base = hl + (size_t)tb * 64 * D_DIM + d;
  float carry = 0.0f;
  for (int c = 0; c < 64; ++c) {
    float* p = base + (size_t)c * D_DIM;
    float tmp = *p;
    *p = carry;
    carry = aT * carry + tmp;
  }
}

__global__ __launch_bounds__(256) void scan3_kernel(
    const float* __restrict__ ap0, const float* __restrict__ bp0,
    const float* __restrict__ cp0, const float* __restrict__ dp0,
    const float* __restrict__ ap1, const float* __restrict__ bp1,
    const float* __restrict__ cp1, const float* __restrict__ dp1,
    __bf16* __restrict__ u0, __bf16* __restrict__ u1,
    const float* __restrict__ hl) {
  int idx = blockIdx.x * 256 + threadIdx.x;
  int d = idx % D_DIM;
  int rest = idx / D_DIM;
  int chunk = rest & 63;
  int tb = rest >> 6;
  int b = tb & 7;
  int tensor = tb >> 3;
  const float* ap = tensor ? ap1 : ap0;
  const float* bp = tensor ? bp1 : bp0;
  const float* cp = tensor ? cp1 : cp0;
  const float* dp = tensor ? dp1 : dp0;
  __bf16* u = (tensor ? u1 : u0) +
      ((size_t)(b * L_SEQ + chunk * CHUNK)) * D_DIM + d;
  float a  = 1.0f / (1.0f + expf(-ap[d]));
  float bb = bp[d];
  float cc = cp[d];
  float dd = dp[d];
  float h = hl[(size_t)idx];
  for (int t = 0; t < CHUNK; ++t) {
    float uv = (float)u[(size_t)t * D_DIM];
    h = a * h + bb * uv;
    u[(size_t)t * D_DIM] = (__bf16)(cc * h + dd * uv);
  }
}

// ---------------- gating: y = (f + flip_L(bb)) * zg ----------------
__global__ __launch_bounds__(256) void gate_kernel(const __bf16* __restrict__ f,
                                                   const __bf16* __restrict__ bbuf,
                                                   const __bf16* __restrict__ zg,
                                                   __bf16* __restrict__ y) {
  size_t idx = (size_t)blockIdx.x * 256 + threadIdx.x;
  int d = (int)(idx % D_DIM);
  size_t rl = idx / D_DIM;
  int l = (int)(rl & (L_SEQ - 1));
  size_t b = rl >> 12;
  size_t src = ((b << 12) + (size_t)(L_SEQ - 1 - l)) * D_DIM + d;
  float v = ((float)f[idx] + (float)bbuf[src]) * (float)zg[idx];
  y[idx] = (__bf16)v;
}

// ---------------- weight transposes (fp32 in -> bf16 out) ----------------
__global__ __launch_bounds__(256) void tr_kernel(const float* __restrict__ in,
                                                 __bf16* __restrict__ out,
                                                 int Kdim, int Ndim) {
  int idx = blockIdx.x * 256 + threadIdx.x;
  if (idx >= Kdim * Ndim) return;
  int n = idx / Kdim;
  int k = idx - n * Kdim;
  out[idx] = (__bf16)in[(size_t)k * Ndim + n];
}

__global__ __launch_bounds__(256) void trconv_kernel(const float* __restrict__ in,
                                                     __bf16* __restrict__ out) {
  int idx = blockIdx.x * 256 + threadIdx.x;
  if (idx >= D_DIM * 2304) return;
  int o = idx / 2304;
  int rem = idx - o * 2304;
  int k = rem / D_DIM;
  int i = rem - k * D_DIM;
  out[idx] = (__bf16)in[(size_t)o * 2304 + i * 3 + k];
}

__global__ void zero_kernel(__bf16* z) { z[threadIdx.x] = (__bf16)0.0f; }

extern "C" void kernel_launch(void* const* d_in, const int* in_sizes, int n_in,
                              void* d_out, int out_size, void* d_ws, size_t ws_size,
                              hipStream_t stream) {
  const float* x    = (const float*)d_in[0];
  const float* ln_g = (const float*)d_in[1];
  const float* ln_b = (const float*)d_in[2];
  const float* Wi   = (const float*)d_in[3];
  const float* bi   = (const float*)d_in[4];
  const float* Wf   = (const float*)d_in[5];
  const float* bfc  = (const float*)d_in[6];
  const float* af   = (const float*)d_in[7];
  const float* bfp  = (const float*)d_in[8];
  const float* cfp  = (const float*)d_in[9];
  const float* dfp  = (const float*)d_in[10];
  const float* Wb   = (const float*)d_in[11];
  const float* bbc  = (const float*)d_in[12];
  const float* ab   = (const float*)d_in[13];
  const float* bbp  = (const float*)d_in[14];
  const float* cbp  = (const float*)d_in[15];
  const float* dbp  = (const float*)d_in[16];
  const float* Wo   = (const float*)d_in[17];
  const float* bo   = (const float*)d_in[18];
  float* out = (float*)d_out;

  char* ws = (char*)d_ws;
  const size_t BLD = (size_t)B_SZ * L_SEQ * D_DIM;   // 25165824
  __bf16* ws0 = (__bf16*)(ws);                       // xn, then f
  __bf16* ws1 = (__bf16*)(ws + BLD * 2);             // xg, then y
  __bf16* ws2 = (__bf16*)(ws + BLD * 4);             // zg (silu applied)
  __bf16* ws3 = (__bf16*)(ws + BLD * 6);             // bbuf (flipped-time order)
  __bf16* wit = (__bf16*)(ws + BLD * 8);             // Wi^T  (1536 x 768)
  __bf16* wft = wit + (size_t)1536 * 768;            // Wf reshaped (768 x 2304)
  __bf16* wbt = wft + (size_t)768 * 2304;            // Wb reshaped
  __bf16* wot = wbt + (size_t)768 * 2304;            // Wo^T (768 x 768)
  __bf16* zbuf = wot + (size_t)768 * 768;            // 256B zero pad for conv halo
  float* hl = (float*)(ws + BLD * 2);                // scan scratch aliases dead xg
  const size_t needed = BLD * 8 +
      ((size_t)1536 * 768 + 2 * (size_t)768 * 2304 + (size_t)768 * 768) * 2 + 256;
  if (ws_size < needed) return;

  zero_kernel<<<1, 128, 0, stream>>>(zbuf);
  tr_kernel<<<(768 * 1536 + 255) / 256, 256, 0, stream>>>(Wi, wit, 768, 1536);
  trconv_kernel<<<(768 * 2304 + 255) / 256, 256, 0, stream>>>(Wf, wft);
  trconv_kernel<<<(768 * 2304 + 255) / 256, 256, 0, stream>>>(Wb, wbt);
  tr_kernel<<<(768 * 768 + 255) / 256, 256, 0, stream>>>(Wo, wot, 768, 768);

  ln_kernel<<<M_ROWS, 256, 0, stream>>>(x, ln_g, ln_b, ws0);

  // proj = xn@Wi + bi -> xg (ws1), zg = silu(z) (ws2)
  gemm_kernel<0><<<dim3(1536 / 128, M_ROWS / 128), 256, 0, stream>>>(
      ws0, wit, bi, nullptr, ws1, ws2, nullptr, zbuf, 768);

  // convs as GEMM over virtual K=2304
  gemm_kernel<1><<<dim3(768 / 128, M_ROWS / 128), 256, 0, stream>>>(
      ws1, wft, bfc, nullptr, ws0, nullptr, nullptr, zbuf, 2304);
  gemm_kernel<2><<<dim3(768 / 128, M_ROWS / 128), 256, 0, stream>>>(
      ws1, wbt, bbc, nullptr, ws3, nullptr, nullptr, zbuf, 2304);

  // chunked parallel SSM scans, in-place on ws0/ws3
  {
    const int n1 = 2 * B_SZ * 64 * D_DIM;
    scan1_kernel<<<n1 / 256, 256, 0, stream>>>(af, bfp, ab, bbp, ws0, ws3, hl);
    const int n2 = 2 * B_SZ * D_DIM;
    scan2_kernel<<<n2 / 256, 256, 0, stream>>>(af, ab, hl);
    scan3_kernel<<<n1 / 256, 256, 0, stream>>>(af, bfp, cfp, dfp,
                                               ab, bbp, cbp, dbp,
                                               ws0, ws3, hl);
  }

  gate_kernel<<<(unsigned)(BLD / 256), 256, 0, stream>>>(ws0, ws3, ws2, ws1);

  // out = y@Wo + bo + x  (fp32 output)
  gemm_kernel<3><<<dim3(768 / 128, M_ROWS / 128), 256, 0, stream>>>(
      ws1, wot, bo, x, nullptr, nullptr, out, zbuf, 768);
}